// Round 5
// baseline (2158.849 us; speedup 1.0000x reference)
//
#include <hip/hip_runtime.h>

#define NN 4096
#define TT 12
#define CC 32
#define WW 10            // T-2 windows
#define K3 12288         // 3*N
#define NCOL 640         // B*W*C
#define SA 4096.0f       // adj scale (2^12)
#define SX 1024.0f       // activation scale (2^10)
#define BM 48
#define BK 32
#define NT (K3 / BK)     // 384 k-steps

typedef _Float16 half8 __attribute__((ext_vector_type(8)));
typedef _Float16 half4_t __attribute__((ext_vector_type(4)));
typedef float floatx4 __attribute__((ext_vector_type(4)));

// ---------------- adj fp32 -> fp16 (scaled) ----------------
__global__ void k_conv_adj(const float* __restrict__ adj, _Float16* __restrict__ a16) {
    long n4 = (long)K3 * K3 / 4;
    long i = (long)blockIdx.x * blockDim.x + threadIdx.x;
    long stride = (long)gridDim.x * blockDim.x;
    const float4* src = (const float4*)adj;
    half4_t* dst = (half4_t*)a16;
    for (; i < n4; i += stride) {
        float4 v = src[i];
        half4_t h;
        h[0] = (_Float16)(v.x * SA);
        h[1] = (_Float16)(v.y * SA);
        h[2] = (_Float16)(v.z * SA);
        h[3] = (_Float16)(v.w * SA);
        dst[i] = h;
    }
}

// ---------------- build X0^T [NCOL][K3] fp16 ----------------
__global__ void k_prep(const float* __restrict__ data, const float* __restrict__ temb,
                       const float* __restrict__ semb, _Float16* __restrict__ x0t) {
    __shared__ float sb[CC][64 + 1];
    int z = blockIdx.y;                 // 0..59
    int b = z / 30; int r = z % 30; int w = r / 3; int j = r % 3;
    int t = w + j;
    int n0 = blockIdx.x * 64;
    int tid = threadIdx.x;
    for (int e = tid; e < 64 * CC; e += 256) {
        int nl = e >> 5, c = e & 31;
        float v = data[((long)(b * TT + t) * NN + n0 + nl) * CC + c]
                + temb[t * CC + c] + semb[(n0 + nl) * CC + c];
        sb[c][nl] = v;
    }
    __syncthreads();
    int bw = b * WW + w;
    for (int e = tid; e < 64 * CC; e += 256) {
        int c = e >> 6, nl = e & 63;
        x0t[(long)(bw * CC + c) * K3 + j * NN + n0 + nl] = (_Float16)sb[c][nl];
    }
}

// ---------------- fused GEMM + W-GEMM + GLU, register-pipelined, no-LDS main loop ---
// Block: 256 thr / 4 waves. Wave w owns output cols [n0 + w*80, +80). BM=48 rows.
// A and B fragments loaded global->reg directly (16 full 64B lines per gather),
// 2-deep ping-pong pipeline, compiler-counted vmcnt, zero barriers in main loop.
template <int MODE>
__global__ __launch_bounds__(256, 2) void k_gemm_glu(
    const _Float16* __restrict__ A, const _Float16* __restrict__ BT,
    const float* __restrict__ Wt, const float* __restrict__ bias,
    _Float16* __restrict__ outH,
    const _Float16* __restrict__ x1, const _Float16* __restrict__ x2,
    float* __restrict__ outF,
    float invS, int Mvalid)
{
    __shared__ float scr[BM * 321];          // 61.6 KB epilogue transpose scratch
    __shared__ float WB[CC * 64 + 64];       // 8.4 KB
    const int SCRW = 321;

    int tid = threadIdx.x;
    int lane = tid & 63, wid = tid >> 6;

    // bijective XCD-chunked swizzle; (mt, nh) half-pairs adjacent -> same XCD L2 for A
    int nblk = gridDim.x;
    int q = nblk >> 3, r = nblk & 7;
    int xcd = blockIdx.x & 7, bi = blockIdx.x >> 3;
    int lin = (xcd < r ? xcd * (q + 1) : r * (q + 1) + (xcd - r) * q) + bi;
    int mt = lin >> 1, nh = lin & 1;
    long m0 = (long)mt * BM;
    int n0 = nh * 320;

    for (int e = tid; e < CC * 64; e += 256) WB[e] = Wt[e];
    if (tid < 64) WB[CC * 64 + tid] = bias[tid];
    // (epilogue __syncthreads covers WB visibility)

    int fr = lane & 15, kq = lane >> 4;

    const _Float16* aP0 = A + (m0 +  0 + fr) * (long)K3 + kq * 8;
    const _Float16* aP1 = A + (m0 + 16 + fr) * (long)K3 + kq * 8;
    const _Float16* aP2 = A + (m0 + 32 + fr) * (long)K3 + kq * 8;
    int cb0 = n0 + wid * 80 + fr;
    const _Float16* bP0 = BT + (long)(cb0 +  0) * K3 + kq * 8;
    const _Float16* bP1 = BT + (long)(cb0 + 16) * K3 + kq * 8;
    const _Float16* bP2 = BT + (long)(cb0 + 32) * K3 + kq * 8;
    const _Float16* bP3 = BT + (long)(cb0 + 48) * K3 + kq * 8;
    const _Float16* bP4 = BT + (long)(cb0 + 64) * K3 + kq * 8;

    floatx4 acc[3][5] = {};

#define LOAD_SET(sa0, sa1, sa2, sb0, sb1, sb2, sb3, sb4, OFF)      \
    do {                                                           \
        sa0 = *(const half8*)(aP0 + (OFF));                        \
        sa1 = *(const half8*)(aP1 + (OFF));                        \
        sa2 = *(const half8*)(aP2 + (OFF));                        \
        sb0 = *(const half8*)(bP0 + (OFF));                        \
        sb1 = *(const half8*)(bP1 + (OFF));                        \
        sb2 = *(const half8*)(bP2 + (OFF));                        \
        sb3 = *(const half8*)(bP3 + (OFF));                        \
        sb4 = *(const half8*)(bP4 + (OFF));                        \
    } while (0)

#define MFMA_SET(sa0, sa1, sa2, sb0, sb1, sb2, sb3, sb4)                              \
    do {                                                                              \
        acc[0][0] = __builtin_amdgcn_mfma_f32_16x16x32_f16(sa0, sb0, acc[0][0],0,0,0);\
        acc[0][1] = __builtin_amdgcn_mfma_f32_16x16x32_f16(sa0, sb1, acc[0][1],0,0,0);\
        acc[0][2] = __builtin_amdgcn_mfma_f32_16x16x32_f16(sa0, sb2, acc[0][2],0,0,0);\
        acc[0][3] = __builtin_amdgcn_mfma_f32_16x16x32_f16(sa0, sb3, acc[0][3],0,0,0);\
        acc[0][4] = __builtin_amdgcn_mfma_f32_16x16x32_f16(sa0, sb4, acc[0][4],0,0,0);\
        acc[1][0] = __builtin_amdgcn_mfma_f32_16x16x32_f16(sa1, sb0, acc[1][0],0,0,0);\
        acc[1][1] = __builtin_amdgcn_mfma_f32_16x16x32_f16(sa1, sb1, acc[1][1],0,0,0);\
        acc[1][2] = __builtin_amdgcn_mfma_f32_16x16x32_f16(sa1, sb2, acc[1][2],0,0,0);\
        acc[1][3] = __builtin_amdgcn_mfma_f32_16x16x32_f16(sa1, sb3, acc[1][3],0,0,0);\
        acc[1][4] = __builtin_amdgcn_mfma_f32_16x16x32_f16(sa1, sb4, acc[1][4],0,0,0);\
        acc[2][0] = __builtin_amdgcn_mfma_f32_16x16x32_f16(sa2, sb0, acc[2][0],0,0,0);\
        acc[2][1] = __builtin_amdgcn_mfma_f32_16x16x32_f16(sa2, sb1, acc[2][1],0,0,0);\
        acc[2][2] = __builtin_amdgcn_mfma_f32_16x16x32_f16(sa2, sb2, acc[2][2],0,0,0);\
        acc[2][3] = __builtin_amdgcn_mfma_f32_16x16x32_f16(sa2, sb3, acc[2][3],0,0,0);\
        acc[2][4] = __builtin_amdgcn_mfma_f32_16x16x32_f16(sa2, sb4, acc[2][4],0,0,0);\
    } while (0)

    half8 aA0, aA1, aA2, bA0, bA1, bA2, bA3, bA4;
    half8 aB0, aB1, aB2, bB0, bB1, bB2, bB3, bB4;

    // prologue: steps 0 and 1; then pointers -> step 2
    LOAD_SET(aA0, aA1, aA2, bA0, bA1, bA2, bA3, bA4, 0);
    LOAD_SET(aB0, aB1, aB2, bB0, bB1, bB2, bB3, bB4, BK);
    aP0 += 2 * BK; aP1 += 2 * BK; aP2 += 2 * BK;
    bP0 += 2 * BK; bP1 += 2 * BK; bP2 += 2 * BK; bP3 += 2 * BK; bP4 += 2 * BK;

#pragma unroll 1
    for (int t = 0; t + 3 < NT; t += 2) {
        // consume step t (set A), refill set A for step t+2
        MFMA_SET(aA0, aA1, aA2, bA0, bA1, bA2, bA3, bA4);
        LOAD_SET(aA0, aA1, aA2, bA0, bA1, bA2, bA3, bA4, 0);
        // consume step t+1 (set B), refill set B for step t+3
        MFMA_SET(aB0, aB1, aB2, bB0, bB1, bB2, bB3, bB4);
        LOAD_SET(aB0, aB1, aB2, bB0, bB1, bB2, bB3, bB4, BK);
        aP0 += 2 * BK; aP1 += 2 * BK; aP2 += 2 * BK;
        bP0 += 2 * BK; bP1 += 2 * BK; bP2 += 2 * BK; bP3 += 2 * BK; bP4 += 2 * BK;
    }
    // tail: steps NT-2, NT-1
    MFMA_SET(aA0, aA1, aA2, bA0, bA1, bA2, bA3, bA4);
    MFMA_SET(aB0, aB1, aB2, bB0, bB1, bB2, bB3, bB4);
#undef LOAD_SET
#undef MFMA_SET

    // -------- epilogue: LDS-transpose acc, tiny W-GEMM + GLU --------
    int rb = (lane >> 4) * 4, cb = lane & 15;
    __syncthreads();
#pragma unroll
    for (int ms = 0; ms < 3; ++ms)
#pragma unroll
        for (int ns = 0; ns < 5; ++ns)
#pragma unroll
            for (int i = 0; i < 4; ++i)
                scr[(ms * 16 + rb + i) * SCRW + wid * 80 + ns * 16 + cb] = acc[ms][ns][i];
    __syncthreads();

    for (int e = tid; e < 480; e += 256) {
        int row = e % 48;
        int bwl = e / 48;            // 0..9
        int bw = nh * 10 + bwl;
        long m = m0 + row;
        float g[CC];
#pragma unroll
        for (int c = 0; c < CC; ++c) g[c] = scr[row * SCRW + bwl * 32 + c] * invS;
        float y[64];
#pragma unroll
        for (int o = 0; o < 64; ++o) y[o] = WB[CC * 64 + o];
#pragma unroll
        for (int c = 0; c < CC; ++c) {
            float gv = g[c];
#pragma unroll
            for (int o = 0; o < 64; ++o) y[o] = fmaf(gv, WB[c * 64 + o], y[o]);
        }
        if (MODE == 0) {
#pragma unroll
            for (int c = 0; c < CC; ++c) {
                float rr = y[c] * (1.f / (1.f + __expf(-y[c + 32])));
                outH[(long)(bw * CC + c) * K3 + m] = (_Float16)(rr * SX);
            }
        } else {
            if (m < Mvalid) {
                float res[CC];
#pragma unroll
                for (int c = 0; c < CC; ++c) {
                    float rr = y[c] * (1.f / (1.f + __expf(-y[c + 32])));
                    float v1 = (float)x1[(long)(bw * CC + c) * K3 + NN + m] * (1.f / SX);
                    float v2 = (float)x2[(long)(bw * CC + c) * K3 + NN + m] * (1.f / SX);
                    res[c] = fmaxf(rr, fmaxf(v1, v2));
                }
                float4* op = (float4*)(outF + ((long)bw * NN + m) * CC);
#pragma unroll
                for (int qv = 0; qv < CC / 4; ++qv)
                    op[qv] = make_float4(res[qv * 4 + 0], res[qv * 4 + 1], res[qv * 4 + 2], res[qv * 4 + 3]);
            }
        }
    }
}

extern "C" void kernel_launch(void* const* d_in, const int* in_sizes, int n_in,
                              void* d_out, int out_size, void* d_ws, size_t ws_size,
                              hipStream_t stream)
{
    const float* data = (const float*)d_in[0];
    const float* adj  = (const float*)d_in[1];
    const float* temb = (const float*)d_in[2];
    const float* semb = (const float*)d_in[3];
    const float* W0 = (const float*)d_in[4];
    const float* b0 = (const float*)d_in[5];
    const float* W1 = (const float*)d_in[6];
    const float* b1 = (const float*)d_in[7];
    const float* W2 = (const float*)d_in[8];
    const float* b2 = (const float*)d_in[9];
    float* out = (float*)d_out;
    (void)ws_size; (void)in_sizes; (void)n_in; (void)out_size;

    char* ws = (char*)d_ws;
    _Float16* A16 = (_Float16*)ws;  ws += (size_t)K3 * K3 * 2;        // 302 MB
    _Float16* X0  = (_Float16*)ws;  ws += (size_t)NCOL * K3 * 2;      // 15.7 MB
    _Float16* X1  = (_Float16*)ws;  ws += (size_t)NCOL * K3 * 2;
    _Float16* X2  = (_Float16*)ws;  ws += (size_t)NCOL * K3 * 2;

    k_conv_adj<<<4096, 256, 0, stream>>>(adj, A16);
    k_prep<<<dim3(64, 60), 256, 0, stream>>>(data, temb, semb, X0);

    // layer 1: 256 m-tiles x 2 n-halves
    k_gemm_glu<0><<<512, 256, 0, stream>>>(A16, X0, W0, b0, X1,
                                           nullptr, nullptr, nullptr, 1.f / SA, K3);
    // layer 2
    k_gemm_glu<0><<<512, 256, 0, stream>>>(A16, X1, W1, b1, X2,
                                           nullptr, nullptr, nullptr, 1.f / (SA * SX), K3);
    // layer 3: middle N rows of adj; fused GLU + 3-way max + final layout
    k_gemm_glu<1><<<172, 256, 0, stream>>>(A16 + (size_t)NN * K3, X2, W2, b2, nullptr,
                                           X1, X2, out, 1.f / (SA * SX), NN);
}

// Round 6
// 1437.988 us; speedup vs baseline: 1.5013x; 1.5013x over previous
//
#include <hip/hip_runtime.h>

#define NN 4096
#define TT 12
#define CC 32
#define WW 10            // T-2 windows
#define K3 12288         // 3*N
#define NCOL 640         // B*W*C
#define SA 4096.0f       // adj scale (2^12)
#define SX 1024.0f       // activation scale (2^10)
#define BM 48
#define BNH 320          // N-half per block
#define BK 32
#define NT (K3 / BK)     // 384 k-steps

typedef _Float16 half8 __attribute__((ext_vector_type(8)));
typedef _Float16 half4_t __attribute__((ext_vector_type(4)));
typedef float floatx4 __attribute__((ext_vector_type(4)));

// ---------------- adj fp32 -> fp16 (scaled) ----------------
__global__ void k_conv_adj(const float* __restrict__ adj, _Float16* __restrict__ a16) {
    long n4 = (long)K3 * K3 / 4;
    long i = (long)blockIdx.x * blockDim.x + threadIdx.x;
    long stride = (long)gridDim.x * blockDim.x;
    const float4* src = (const float4*)adj;
    half4_t* dst = (half4_t*)a16;
    for (; i < n4; i += stride) {
        float4 v = src[i];
        half4_t h;
        h[0] = (_Float16)(v.x * SA);
        h[1] = (_Float16)(v.y * SA);
        h[2] = (_Float16)(v.z * SA);
        h[3] = (_Float16)(v.w * SA);
        dst[i] = h;
    }
}

// ---------------- build X0^T [NCOL][K3] fp16 ----------------
__global__ void k_prep(const float* __restrict__ data, const float* __restrict__ temb,
                       const float* __restrict__ semb, _Float16* __restrict__ x0t) {
    __shared__ float sb[CC][64 + 1];
    int z = blockIdx.y;                 // 0..59
    int b = z / 30; int r = z % 30; int w = r / 3; int j = r % 3;
    int t = w + j;
    int n0 = blockIdx.x * 64;
    int tid = threadIdx.x;
    for (int e = tid; e < 64 * CC; e += 256) {
        int nl = e >> 5, c = e & 31;
        float v = data[((long)(b * TT + t) * NN + n0 + nl) * CC + c]
                + temb[t * CC + c] + semb[(n0 + nl) * CC + c];
        sb[c][nl] = v;
    }
    __syncthreads();
    int bw = b * WW + w;
    for (int e = tid; e < 64 * CC; e += 256) {
        int c = e >> 6, nl = e & 63;
        x0t[(long)(bw * CC + c) * K3 + j * NN + n0 + nl] = (_Float16)sb[c][nl];
    }
}

__device__ __forceinline__ void gload_lds16(const _Float16* g, _Float16* l) {
    __builtin_amdgcn_global_load_lds(
        (const __attribute__((address_space(1))) void*)g,
        (__attribute__((address_space(3))) void*)l, 16, 0, 0);
}

// ---------------- fused GEMM (A[48xK] @ BT[320xK]^T) + W-GEMM + GLU ----------------
// 3-deep LDS pipeline, ONE barrier per k-step, counted vmcnt, setprio MFMA cluster.
template <int MODE>
__global__ __launch_bounds__(256, 2) void k_gemm_glu(
    const _Float16* __restrict__ A, const _Float16* __restrict__ BT,
    const float* __restrict__ Wt, const float* __restrict__ bias,
    _Float16* __restrict__ outH,
    const _Float16* __restrict__ x1, const _Float16* __restrict__ x2,
    float* __restrict__ outF,
    float invS, int Mvalid)
{
    // per buffer: A [48][32] = 1536 halves, then B [320][32] = 10240 halves
    __shared__ __attribute__((aligned(16))) _Float16 AB[3][11776];   // 69.0 KB
    __shared__ float WB[CC * 64 + 64];                               // 8.3 KB

    int tid = threadIdx.x;
    int lane = tid & 63, wid = tid >> 6;

    // bijective XCD-chunked block swizzle; (mt,nh) pairs contiguous per XCD
    int nblk = gridDim.x;
    int q = nblk >> 3, r = nblk & 7;
    int xcd = blockIdx.x & 7, bi = blockIdx.x >> 3;
    int lin = (xcd < r ? xcd * (q + 1) : r * (q + 1) + (xcd - r) * q) + bi;
    int mt = lin >> 1, nh = lin & 1;
    long m0 = (long)mt * BM;
    int n0 = nh * BNH;

    for (int e = tid; e < CC * 64; e += 256) WB[e] = Wt[e];
    if (tid < 64) WB[CC * 64 + tid] = bias[tid];

    // ---- staging source pointers (swizzled k-chunk in GLOBAL address; LDS linear)
    int rowA = tid >> 2, kbA_st = tid & 3;
    int ksA = kbA_st ^ ((rowA >> 1) & 3);
    const _Float16* aS = A + (m0 + rowA) * (long)K3 + ksA * 8;
    const _Float16* bS[5];
#pragma unroll
    for (int i = 0; i < 5; ++i) {
        int ci = i * 256 + tid;
        int row = ci >> 2, kb = ci & 3;
        int ks = kb ^ ((row >> 1) & 3);
        bS[i] = BT + (long)(n0 + row) * K3 + ks * 8;
    }

#define STAGE(bufi, kOff)                                                   \
    do {                                                                    \
        _Float16* bp = &AB[bufi][0];                                        \
        gload_lds16(bS[0] + (kOff), bp + 1536 + (0 * 256 + wid * 64) * 8);  \
        gload_lds16(bS[1] + (kOff), bp + 1536 + (1 * 256 + wid * 64) * 8);  \
        gload_lds16(bS[2] + (kOff), bp + 1536 + (2 * 256 + wid * 64) * 8);  \
        gload_lds16(bS[3] + (kOff), bp + 1536 + (3 * 256 + wid * 64) * 8);  \
        gload_lds16(bS[4] + (kOff), bp + 1536 + (4 * 256 + wid * 64) * 8);  \
        if (wid < 3) gload_lds16(aS + (kOff), bp + wid * 512);              \
    } while (0)

    // ---- fragment read offsets (halves), swizzle-matched
    int fr = lane & 15, kq = lane >> 4;
    int kbs = kq ^ ((fr >> 1) & 3);      // invariant under row += 16 / +80
    int aOff[3], bOff[5];
#pragma unroll
    for (int ms = 0; ms < 3; ++ms) aOff[ms] = (ms * 16 + fr) * 32 + kbs * 8;
#pragma unroll
    for (int ns = 0; ns < 5; ++ns) bOff[ns] = 1536 + (wid * 80 + ns * 16 + fr) * 32 + kbs * 8;

    floatx4 acc[3][5] = {};

    STAGE(0, 0);
    STAGE(1, BK);

    int cur = 0;
#pragma unroll 1
    for (int t = 0; t < NT; ++t) {
        // wait: own stage(t) landed (FIFO: allow stage(t+1)'s loads in flight)
        if (t < NT - 1) {
            if (wid < 3) asm volatile("s_waitcnt vmcnt(6)" ::: "memory");
            else         asm volatile("s_waitcnt vmcnt(5)" ::: "memory");
        } else {
            asm volatile("s_waitcnt vmcnt(0)" ::: "memory");
        }
        // single barrier: tile t complete AND everyone's t-1 reads done
        asm volatile("s_barrier" ::: "memory");

        // prefetch tile t+2 into the buffer that held t-1 (freed by this barrier)
        int nxt = (cur == 0) ? 2 : cur - 1;          // (cur+2)%3
        if (t + 2 < NT) STAGE(nxt, (long)(t + 2) * BK);

        const _Float16* P = &AB[cur][0];
        half8 af[3], bf[5];
#pragma unroll
        for (int ms = 0; ms < 3; ++ms) af[ms] = *(const half8*)(P + aOff[ms]);
#pragma unroll
        for (int ns = 0; ns < 5; ++ns) bf[ns] = *(const half8*)(P + bOff[ns]);

        __builtin_amdgcn_s_setprio(1);
#pragma unroll
        for (int ms = 0; ms < 3; ++ms)
#pragma unroll
            for (int ns = 0; ns < 5; ++ns)
                acc[ms][ns] = __builtin_amdgcn_mfma_f32_16x16x32_f16(af[ms], bf[ns], acc[ms][ns], 0, 0, 0);
        __builtin_amdgcn_s_setprio(0);

        cur = (cur == 2) ? 0 : cur + 1;
    }
#undef STAGE

    // -------- epilogue: LDS-transpose acc, tiny W-GEMM + GLU --------
    float* scr = (float*)AB;          // 48 x 321 floats = 61.6 KB <= 69 KB
    const int SCRW = 321;
    int rb = (lane >> 4) * 4, cb = lane & 15;

    __syncthreads();
#pragma unroll
    for (int ms = 0; ms < 3; ++ms)
#pragma unroll
        for (int ns = 0; ns < 5; ++ns)
#pragma unroll
            for (int i = 0; i < 4; ++i)
                scr[(ms * 16 + rb + i) * SCRW + wid * 80 + ns * 16 + cb] = acc[ms][ns][i];
    __syncthreads();

    for (int e = tid; e < 480; e += 256) {
        int row = e % 48;
        int bwl = e / 48;            // 0..9
        int bw = nh * 10 + bwl;
        long m = m0 + row;
        float g[CC];
#pragma unroll
        for (int c = 0; c < CC; ++c) g[c] = scr[row * SCRW + bwl * 32 + c] * invS;
        float y[64];
#pragma unroll
        for (int o = 0; o < 64; ++o) y[o] = WB[CC * 64 + o];
#pragma unroll
        for (int c = 0; c < CC; ++c) {
            float gv = g[c];
#pragma unroll
            for (int o = 0; o < 64; ++o) y[o] = fmaf(gv, WB[c * 64 + o], y[o]);
        }
        if (MODE == 0) {
#pragma unroll
            for (int c = 0; c < CC; ++c) {
                float rr = y[c] * (1.f / (1.f + __expf(-y[c + 32])));
                outH[(long)(bw * CC + c) * K3 + m] = (_Float16)(rr * SX);
            }
        } else {
            if (m < Mvalid) {
                float res[CC];
#pragma unroll
                for (int c = 0; c < CC; ++c) {
                    float rr = y[c] * (1.f / (1.f + __expf(-y[c + 32])));
                    float v1 = (float)x1[(long)(bw * CC + c) * K3 + NN + m] * (1.f / SX);
                    float v2 = (float)x2[(long)(bw * CC + c) * K3 + NN + m] * (1.f / SX);
                    res[c] = fmaxf(rr, fmaxf(v1, v2));
                }
                float4* op = (float4*)(outF + ((long)bw * NN + m) * CC);
#pragma unroll
                for (int qv = 0; qv < CC / 4; ++qv)
                    op[qv] = make_float4(res[qv * 4 + 0], res[qv * 4 + 1], res[qv * 4 + 2], res[qv * 4 + 3]);
            }
        }
    }
}

extern "C" void kernel_launch(void* const* d_in, const int* in_sizes, int n_in,
                              void* d_out, int out_size, void* d_ws, size_t ws_size,
                              hipStream_t stream)
{
    const float* data = (const float*)d_in[0];
    const float* adj  = (const float*)d_in[1];
    const float* temb = (const float*)d_in[2];
    const float* semb = (const float*)d_in[3];
    const float* W0 = (const float*)d_in[4];
    const float* b0 = (const float*)d_in[5];
    const float* W1 = (const float*)d_in[6];
    const float* b1 = (const float*)d_in[7];
    const float* W2 = (const float*)d_in[8];
    const float* b2 = (const float*)d_in[9];
    float* out = (float*)d_out;
    (void)ws_size; (void)in_sizes; (void)n_in; (void)out_size;

    char* ws = (char*)d_ws;
    _Float16* A16 = (_Float16*)ws;  ws += (size_t)K3 * K3 * 2;        // 302 MB
    _Float16* X0  = (_Float16*)ws;  ws += (size_t)NCOL * K3 * 2;      // 15.7 MB
    _Float16* X1  = (_Float16*)ws;  ws += (size_t)NCOL * K3 * 2;
    _Float16* X2  = (_Float16*)ws;  ws += (size_t)NCOL * K3 * 2;

    k_conv_adj<<<4096, 256, 0, stream>>>(adj, A16);
    k_prep<<<dim3(64, 60), 256, 0, stream>>>(data, temb, semb, X0);

    // layer 1: 256 m-tiles x 2 n-halves
    k_gemm_glu<0><<<512, 256, 0, stream>>>(A16, X0, W0, b0, X1,
                                           nullptr, nullptr, nullptr, 1.f / SA, K3);
    // layer 2
    k_gemm_glu<0><<<512, 256, 0, stream>>>(A16, X1, W1, b1, X2,
                                           nullptr, nullptr, nullptr, 1.f / (SA * SX), K3);
    // layer 3: middle N rows of adj; fused GLU + 3-way max + final layout
    k_gemm_glu<1><<<172, 256, 0, stream>>>(A16 + (size_t)NN * K3, X2, W2, b2, nullptr,
                                           X1, X2, out, 1.f / (SA * SX), NN);
}